// Round 6
// baseline (764.175 us; speedup 1.0000x reference)
//
#include <hip/hip_runtime.h>
#include <hip/hip_bf16.h>
#include <math.h>

#define N_NODES 50000
#define N_EDGES 800000
#define FDIM 53
#define BATCH 128
#define HF 212   /* H*F */
#define F2 106   /* 2F  */
#define POOLW 424 /* 212+106+106 */
#define NPK2 220 /* 106 + 106 + 8: U | V | alS | alD */
#define PSTR 32  /* padded bin stride (ints) = 128 B: one L2 line per node */
#define ECS 128  /* U/V bf16 row stride (shorts) = 256 B = 4 L2 lines */

typedef __attribute__((ext_vector_type(8))) short short8;
typedef __attribute__((ext_vector_type(4))) float f32x4;

__device__ __forceinline__ float leaky02(float x){ return x >= 0.f ? x : 0.2f * x; }

__device__ __forceinline__ short f2bf(float x) {
  unsigned u = __float_as_uint(x);
  unsigned r = (u + 0x7fffu + ((u >> 16) & 1u)) >> 16;
  return (short)r;
}
__device__ __forceinline__ float bf2f(short b) {
  return __uint_as_float(((unsigned)(unsigned short)b) << 16);
}
// packed pair f32x2 -> bf16x2 (v_cvt_pk_bf16_f32, RNE)
__device__ __forceinline__ unsigned pk2(float a, float b) {
  union { __hip_bfloat162 h; unsigned u; } c;
  c.h = __float22bfloat162_rn(make_float2(a, b));
  return c.u;
}
// monotonic float<->uint mapping for atomicMax-based float max (handles negatives)
__device__ __forceinline__ unsigned fmap(float f) {
  unsigned u = __float_as_uint(f);
  return (u >> 31) ? ~u : (u | 0x80000000u);
}
__device__ __forceinline__ float funmap(unsigned m) {
  unsigned u = (m >> 31) ? (m & 0x7fffffffu) : ~m;
  return __uint_as_float(u);
}
// LDS-only barrier: waits lgkmcnt(0) (ds ops) but leaves global loads in flight
__device__ __forceinline__ void ldsbar() {
  __builtin_amdgcn_s_waitcnt(0xC07F);   // vmcnt(63) expcnt(7) lgkmcnt(0)
  __builtin_amdgcn_s_barrier();
}

// ---------------------------------------------------------------------------
// cAl[k*8 + sd*4 + h] = sum_f gat_w[k, h*53+f] * (sd? a_dst : a_src)[h,f]
// ---------------------------------------------------------------------------
__global__ void k_cal(const float* __restrict__ gat_w, const float* __restrict__ asrc,
                      const float* __restrict__ adst, float* __restrict__ cAl) {
  int t = threadIdx.x;
  if (t >= FDIM * 8) return;
  int k = t >> 3, r = t & 7, sd = r >> 2, h = r & 3;
  const float* av = sd ? adst : asrc;
  float acc = 0.f;
  for (int f = 0; f < FDIM; ++f) acc += gat_w[k * HF + h * FDIM + f] * av[h * FDIM + f];
  cAl[t] = acc;
}

// ---------------------------------------------------------------------------
// Pack Wp[53][220] = [W1top-W1bot | W1bot | cAl] and bias bp[220]
// ---------------------------------------------------------------------------
__global__ void k_prep(const float* __restrict__ ec_w1, const float* __restrict__ ec_b1,
                       const float* __restrict__ cAl,
                       float* __restrict__ Wp, float* __restrict__ bp) {
  int idx = blockIdx.x * blockDim.x + threadIdx.x;
  if (idx < FDIM * NPK2) {
    int k = idx / NPK2, j = idx % NPK2;
    float v;
    if (j < F2)            v = ec_w1[k * F2 + j] - ec_w1[(FDIM + k) * F2 + j];
    else if (j < 2 * F2)   v = ec_w1[(FDIM + k) * F2 + (j - F2)];
    else                   v = cAl[k * 8 + (j - 2 * F2)];
    Wp[idx] = v;
  }
  if (idx < NPK2) {
    bp[idx] = (idx < F2) ? ec_b1[idx] : 0.f;
  }
}

// ---------------------------------------------------------------------------
// Node-linear GEMM: x[50000x53] @ Wp[53x220] + bp -> U | V | alS | alD.
// Also emits xb (bf16 x rows, 64-short stride) during A-tile staging.
// ---------------------------------------------------------------------------
#define GM 64
#define GN 110
#define GNP 112
#define APAD 57
__global__ __launch_bounds__(256) void k_gemm(
    const float* __restrict__ x, const float* __restrict__ Wp, const float* __restrict__ bp,
    short* __restrict__ xb, short* __restrict__ Ub, short* __restrict__ Vb,
    float* __restrict__ alS, float* __restrict__ alD) {
  __shared__ float As[GM * APAD];
  __shared__ float Ws[FDIM * GNP];
  int mb = blockIdx.x >> 1, nc = blockIdx.x & 1;
  int m0 = mb * GM, n0 = nc * GN;
  int t = threadIdx.x;
  for (int idx = t; idx < GM * FDIM; idx += 256) {
    int m = idx / FDIM, k = idx % FDIM;
    int gm = m0 + m;
    float v = (gm < N_NODES) ? x[(size_t)gm * FDIM + k] : 0.f;
    As[m * APAD + k] = v;
    if (nc == 0 && gm < N_NODES) xb[(size_t)gm * 64 + k] = f2bf(v);
  }
  for (int idx = t; idx < FDIM * GNP; idx += 256) {
    int k = idx / GNP, n = idx % GNP;
    Ws[idx] = (n < GN) ? Wp[k * NPK2 + n0 + n] : 0.f;
  }
  __syncthreads();
  int tx = t & 15, ty = t >> 4;
  int ms = tx * 4, ns = ty * 7;
  float acc[4][7];
#pragma unroll
  for (int i = 0; i < 4; i++)
#pragma unroll
    for (int j = 0; j < 7; j++) acc[i][j] = 0.f;
  for (int k = 0; k < FDIM; k++) {
    float a0 = As[(ms + 0) * APAD + k];
    float a1 = As[(ms + 1) * APAD + k];
    float a2 = As[(ms + 2) * APAD + k];
    float a3 = As[(ms + 3) * APAD + k];
    float b[7];
#pragma unroll
    for (int j = 0; j < 7; j++) b[j] = Ws[k * GNP + ns + j];
#pragma unroll
    for (int j = 0; j < 7; j++) {
      acc[0][j] += a0 * b[j];
      acc[1][j] += a1 * b[j];
      acc[2][j] += a2 * b[j];
      acc[3][j] += a3 * b[j];
    }
  }
  float bj[7];
#pragma unroll
  for (int j = 0; j < 7; j++) {
    int g = n0 + ns + j;
    bj[j] = (g < NPK2) ? bp[g] : 0.f;
  }
#pragma unroll
  for (int i = 0; i < 4; i++) {
    int gm = m0 + ms + i;
    if (gm >= N_NODES) break;
#pragma unroll
    for (int j = 0; j < 7; j++) {
      int g = n0 + ns + j;
      float v = acc[i][j] + bj[j];
      if (g < F2)             Ub[(size_t)gm * ECS + g] = f2bf(v);
      else if (g < 2 * F2)    Vb[(size_t)gm * ECS + (g - F2)] = f2bf(v);
      else if (g < 2 * F2 + 4) alS[gm * 4 + (g - 2 * F2)] = v;
      else if (g < NPK2)      alD[gm * 4 + (g - 2 * F2 - 4)] = v;
    }
  }
}

// ---------------------------------------------------------------------------
// CSR build with L2-line-padded bins: hist -> scan (compacts to rp, turns
// padded slot into scatter cursor) -> scatter. Graph counts via sorted-batch
// boundary detection (no atomics).
// ---------------------------------------------------------------------------
#define SCAN_BLOCKS ((N_NODES + 255) / 256)

__global__ void k_hist(const int* __restrict__ ei, int* __restrict__ histP) {
  int t = blockIdx.x * blockDim.x + threadIdx.x;
  if (t < N_EDGES) atomicAdd(&histP[ei[N_EDGES + t] << 5], 1);
}

__global__ void k_bnd(const int* __restrict__ batch, int* __restrict__ start) {
  int t = blockIdx.x * blockDim.x + threadIdx.x;
  if (t >= N_NODES) return;
  int b = batch[t];
  if (t == 0)
    for (int g = 0; g <= b; g++) start[g] = 0;
  int bn = (t + 1 < N_NODES) ? batch[t + 1] : BATCH;
  for (int g = b + 1; g <= bn; g++) start[g] = t + 1;
}

__global__ __launch_bounds__(256) void k_scan1(const int* __restrict__ histP,
                                               int* __restrict__ rp, int* __restrict__ bsum) {
  __shared__ int buf[256];
  int tid = threadIdx.x;
  int idx = blockIdx.x * 256 + tid;
  int v = (idx < N_NODES) ? histP[idx << 5] : 0;
  buf[tid] = v;
  __syncthreads();
  for (int off = 1; off < 256; off <<= 1) {
    int t2 = (tid >= off) ? buf[tid - off] : 0;
    __syncthreads();
    buf[tid] += t2;
    __syncthreads();
  }
  if (idx < N_NODES) rp[idx] = buf[tid] - v;
  if (tid == 255) bsum[blockIdx.x] = buf[255];
}

__global__ __launch_bounds__(256) void k_scan2(int* __restrict__ bsum) {
  __shared__ int buf[256];
  int tid = threadIdx.x;
  int v = (tid < SCAN_BLOCKS) ? bsum[tid] : 0;
  buf[tid] = v;
  __syncthreads();
  for (int off = 1; off < 256; off <<= 1) {
    int t2 = (tid >= off) ? buf[tid - off] : 0;
    __syncthreads();
    buf[tid] += t2;
    __syncthreads();
  }
  if (tid < SCAN_BLOCKS) bsum[tid] = buf[tid] - v;
}

__global__ __launch_bounds__(256) void k_scan3(const int* __restrict__ bsum,
                                               int* __restrict__ rp, int* __restrict__ histP) {
  int idx = blockIdx.x * 256 + threadIdx.x;
  if (idx < N_NODES) {
    int o = rp[idx] + bsum[blockIdx.x];
    rp[idx] = o;
    histP[idx << 5] = o;   // becomes the (padded) scatter cursor
  }
  if (idx == 0) rp[N_NODES] = N_EDGES;
}

__global__ void k_scatter(const int* __restrict__ ei, int* __restrict__ histP,
                          int* __restrict__ colidx) {
  int e = blockIdx.x * blockDim.x + threadIdx.x;
  if (e >= N_EDGES) return;
  int d = ei[N_EDGES + e];
  int pos = atomicAdd(&histP[d << 5], 1);
  colidx[pos] = ei[e];
}

// ---------------------------------------------------------------------------
// Fused GAT-aggregate + GIN-sum: one edge walk gathering bf16 x rows (128 B
// line each, 6.4 MB table -> L2-resident). GAT uses aggregate-then-transform.
// ---------------------------------------------------------------------------
#define GCH 20
__global__ __launch_bounds__(256) void k_gatgin(
    const short* __restrict__ xb, const float* __restrict__ alS, const float* __restrict__ alD,
    const int* __restrict__ rp, const int* __restrict__ colidx,
    short* __restrict__ agg4, float* __restrict__ agg) {
  int wid = threadIdx.x >> 6, lane = threadIdx.x & 63;
  bool fa = lane < FDIM;
  int i0 = blockIdx.x * GCH;
  int iend = min(i0 + GCH, N_NODES);
  __shared__ int rpG[GCH + 1];
  {
    int t = threadIdx.x, nn = iend - i0;
    if (t <= nn) rpG[t] = rp[i0 + t];
  }
  __syncthreads();
  for (int i = i0 + wid; i < iend; i += 4) {
    int base = rpG[i - i0], deg = rpG[i - i0 + 1] - base;
    float aldi[4], exs[4];
#pragma unroll
    for (int h = 0; h < 4; h++) {
      aldi[h] = alD[i * 4 + h];
      exs[h] = __expf(leaky02(alS[i * 4 + h] + aldi[h]));   // self-loop term
    }
    float xiv = fa ? bf2f(xb[(size_t)i * 64 + lane]) : 0.f;
    float ag0 = exs[0] * xiv, ag1 = exs[1] * xiv, ag2 = exs[2] * xiv, ag3 = exs[3] * xiv;
    float ax = xiv;
    float zl[4] = {0.f, 0.f, 0.f, 0.f};

    for (int c0 = 0; c0 < deg; c0 += 64) {
      int cn = min(64, deg - c0);
      int s = 0;
      float ex0 = 0.f, ex1 = 0.f, ex2 = 0.f, ex3 = 0.f;
      if (lane < cn) {
        s = colidx[base + c0 + lane];
        ex0 = __expf(leaky02(alS[s * 4 + 0] + aldi[0]));
        ex1 = __expf(leaky02(alS[s * 4 + 1] + aldi[1]));
        ex2 = __expf(leaky02(alS[s * 4 + 2] + aldi[2]));
        ex3 = __expf(leaky02(alS[s * 4 + 3] + aldi[3]));
        zl[0] += ex0; zl[1] += ex1; zl[2] += ex2; zl[3] += ex3;
      }
      for (int jj = 0; jj < cn; jj += 4) {
        int sj[4]; float a0[4], a1[4], a2[4], a3[4]; bool vq[4];
#pragma unroll
        for (int q = 0; q < 4; q++) {
          int j2 = jj + q;
          int jc = (j2 < cn) ? j2 : (cn - 1);
          vq[q] = j2 < cn;
          sj[q] = __shfl(s, jc);
          a0[q] = vq[q] ? __shfl(ex0, jc) : 0.f;
          a1[q] = vq[q] ? __shfl(ex1, jc) : 0.f;
          a2[q] = vq[q] ? __shfl(ex2, jc) : 0.f;
          a3[q] = vq[q] ? __shfl(ex3, jc) : 0.f;
        }
        float xg[4];
#pragma unroll
        for (int q = 0; q < 4; q++)
          xg[q] = fa ? bf2f(xb[(size_t)sj[q] * 64 + lane]) : 0.f;
#pragma unroll
        for (int q = 0; q < 4; q++) {
          ag0 += a0[q] * xg[q];
          ag1 += a1[q] * xg[q];
          ag2 += a2[q] * xg[q];
          ag3 += a3[q] * xg[q];
          ax += vq[q] ? xg[q] : 0.f;
        }
      }
    }
#pragma unroll
    for (int off = 32; off >= 1; off >>= 1)
#pragma unroll
      for (int h = 0; h < 4; h++) zl[h] += __shfl_xor(zl[h], off);
    if (fa) {
      float z0 = zl[0] + exs[0] + 1e-16f;
      float z1 = zl[1] + exs[1] + 1e-16f;
      float z2 = zl[2] + exs[2] + 1e-16f;
      float z3 = zl[3] + exs[3] + 1e-16f;
      short* ar = agg4 + (size_t)i * HF;
      ar[0 * FDIM + lane] = f2bf(ag0 / z0);
      ar[1 * FDIM + lane] = f2bf(ag1 / z1);
      ar[2 * FDIM + lane] = f2bf(ag2 / z2);
      ar[3 * FDIM + lane] = f2bf(ag3 / z3);
      agg[(size_t)i * FDIM + lane] = ax;
    }
  }
}

// ---------------------------------------------------------------------------
// GAT transform: grouped (per-head 53x53) GEMM + relu + pooled accumulation
// ---------------------------------------------------------------------------
#define TCOLS 224   /* 4 heads x 56 padded cols */
#define A4S 217     /* As row stride in shorts (odd -> conflict-free) */
__global__ __launch_bounds__(256) void k_gtrans(
    const short* __restrict__ agg4, const float* __restrict__ gat_w,
    const float* __restrict__ bias, const int* __restrict__ batch,
    float* __restrict__ pooled) {
  __shared__ short As[64 * A4S];
  __shared__ float Bs[FDIM * TCOLS];
  __shared__ float psum[4 * TCOLS];
  int m0 = blockIdx.x * 64;
  int t = threadIdx.x;
  for (int idx = t; idx < 4 * TCOLS; idx += 256) psum[idx] = 0.f;
  for (int idx = t; idx < 64 * HF; idx += 256) {
    int m = idx / HF, c = idx % HF;
    int gm = m0 + m;
    As[m * A4S + c] = (gm < N_NODES) ? agg4[(size_t)gm * HF + c] : (short)0;
  }
  for (int idx = t; idx < FDIM * TCOLS; idx += 256) {
    int k = idx / TCOLS, c = idx % TCOLS;
    int h = c / 56, jn = c % 56;
    Bs[idx] = (jn < FDIM) ? gat_w[k * HF + h * FDIM + jn] : 0.f;
  }
  __syncthreads();
  int tx = t & 15, ty = t >> 4;
  int ms = tx * 4, ns = ty * 14;
  int hh = ty >> 2;
  int jnb = (ty & 3) * 14;
  float acc[4][14];
#pragma unroll
  for (int i = 0; i < 4; i++)
#pragma unroll
    for (int j = 0; j < 14; j++) acc[i][j] = 0.f;
  for (int k = 0; k < FDIM; k++) {
    float a0 = bf2f(As[(ms + 0) * A4S + hh * FDIM + k]);
    float a1 = bf2f(As[(ms + 1) * A4S + hh * FDIM + k]);
    float a2 = bf2f(As[(ms + 2) * A4S + hh * FDIM + k]);
    float a3 = bf2f(As[(ms + 3) * A4S + hh * FDIM + k]);
    float b[14];
#pragma unroll
    for (int j = 0; j < 14; j++) b[j] = Bs[k * TCOLS + ns + j];
#pragma unroll
    for (int j = 0; j < 14; j++) {
      acc[0][j] += a0 * b[j];
      acc[1][j] += a1 * b[j];
      acc[2][j] += a2 * b[j];
      acc[3][j] += a3 * b[j];
    }
  }
  float bj[14]; bool jv[14];
#pragma unroll
  for (int j = 0; j < 14; j++) {
    jv[j] = (jnb + j) < FDIM;
    bj[j] = jv[j] ? bias[hh * FDIM + jnb + j] : 0.f;
  }
  int bmin = batch[m0];
  float pj[14];
#pragma unroll
  for (int j = 0; j < 14; j++) pj[j] = 0.f;
  int curb = -1;
#pragma unroll
  for (int i = 0; i < 4; i++) {
    int gm = m0 + ms + i;
    if (gm >= N_NODES) break;
    int b = batch[gm];
    if (b != curb) {
      if (curb >= 0) {
        int slot = curb - bmin;
        if (slot >= 0 && slot < 4) {
#pragma unroll
          for (int j = 0; j < 14; j++)
            if (jv[j]) atomicAdd(&psum[slot * TCOLS + ns + j], pj[j]);
        } else {
          float* pg = pooled + (size_t)curb * POOLW;
#pragma unroll
          for (int j = 0; j < 14; j++)
            if (jv[j]) atomicAdd(&pg[hh * FDIM + jnb + j], pj[j]);
        }
      }
      curb = b;
#pragma unroll
      for (int j = 0; j < 14; j++)
        pj[j] = jv[j] ? fmaxf(acc[i][j] + bj[j], 0.f) : 0.f;
    } else {
#pragma unroll
      for (int j = 0; j < 14; j++)
        if (jv[j]) pj[j] += fmaxf(acc[i][j] + bj[j], 0.f);
    }
  }
  if (curb >= 0) {
    int slot = curb - bmin;
    if (slot >= 0 && slot < 4) {
#pragma unroll
      for (int j = 0; j < 14; j++)
        if (jv[j]) atomicAdd(&psum[slot * TCOLS + ns + j], pj[j]);
    } else {
      float* pg = pooled + (size_t)curb * POOLW;
#pragma unroll
      for (int j = 0; j < 14; j++)
        if (jv[j]) atomicAdd(&pg[hh * FDIM + jnb + j], pj[j]);
    }
  }
  __syncthreads();
  for (int idx = t; idx < 4 * TCOLS; idx += 256) {
    int slot = idx / TCOLS, c = idx % TCOLS;
    int h = c / 56, jn = c % 56;
    float v = psum[idx];
    int b = bmin + slot;
    if (jn < FDIM && b < BATCH && v != 0.f)
      atomicAdd(&pooled[(size_t)b * POOLW + h * FDIM + jn], v);
  }
}

// ---------------------------------------------------------------------------
// GIN (2): h1g = relu(agg @ w1 + b1)
// ---------------------------------------------------------------------------
__global__ __launch_bounds__(256) void k_gin1(
    const float* __restrict__ agg, const float* __restrict__ w1, const float* __restrict__ b1,
    float* __restrict__ h1g) {
  __shared__ float As[64 * APAD];
  __shared__ float Ws[FDIM * 112];
  int m0 = blockIdx.x * 64;
  int t = threadIdx.x;
  for (int idx = t; idx < 64 * FDIM; idx += 256) {
    int m = idx / FDIM, k = idx % FDIM;
    int gm = m0 + m;
    As[m * APAD + k] = (gm < N_NODES) ? agg[(size_t)gm * FDIM + k] : 0.f;
  }
  for (int idx = t; idx < FDIM * 112; idx += 256) {
    int k = idx / 112, n = idx % 112;
    Ws[idx] = (n < F2) ? w1[k * F2 + n] : 0.f;
  }
  __syncthreads();
  int tx = t & 15, ty = t >> 4;
  int ms = tx * 4, ns = ty * 7;
  float acc[4][7];
#pragma unroll
  for (int i = 0; i < 4; i++)
#pragma unroll
    for (int j = 0; j < 7; j++) acc[i][j] = 0.f;
  for (int k = 0; k < FDIM; k++) {
    float a0 = As[(ms + 0) * APAD + k];
    float a1 = As[(ms + 1) * APAD + k];
    float a2 = As[(ms + 2) * APAD + k];
    float a3 = As[(ms + 3) * APAD + k];
    float b[7];
#pragma unroll
    for (int j = 0; j < 7; j++) b[j] = Ws[k * 112 + ns + j];
#pragma unroll
    for (int j = 0; j < 7; j++) {
      acc[0][j] += a0 * b[j];
      acc[1][j] += a1 * b[j];
      acc[2][j] += a2 * b[j];
      acc[3][j] += a3 * b[j];
    }
  }
#pragma unroll
  for (int i = 0; i < 4; i++) {
    int gm = m0 + ms + i;
    if (gm >= N_NODES) break;
#pragma unroll
    for (int j = 0; j < 7; j++) {
      int n = ns + j;
      if (n < F2) h1g[(size_t)gm * F2 + n] = fmaxf(acc[i][j] + b1[n], 0.f);
    }
  }
}

// ---------------------------------------------------------------------------
// GIN (3): h2 = relu(h1g @ w2 + b2) + pooled accumulation (LDS psum)
// ---------------------------------------------------------------------------
#define A2PAD 111
__global__ __launch_bounds__(256) void k_gin2(
    const float* __restrict__ h1g, const float* __restrict__ w2, const float* __restrict__ b2,
    const int* __restrict__ batch, float* __restrict__ pooled) {
  __shared__ float As[64 * A2PAD];
  __shared__ float Ws[F2 * 112];
  __shared__ float psum[4 * 112];
  int m0 = blockIdx.x * 64;
  int t = threadIdx.x;
  for (int idx = t; idx < 4 * 112; idx += 256) psum[idx] = 0.f;
  for (int idx = t; idx < 64 * F2; idx += 256) {
    int m = idx / F2, k = idx % F2;
    int gm = m0 + m;
    As[m * A2PAD + k] = (gm < N_NODES) ? h1g[(size_t)gm * F2 + k] : 0.f;
  }
  for (int idx = t; idx < F2 * 112; idx += 256) {
    int k = idx / 112, n = idx % 112;
    Ws[idx] = (n < F2) ? w2[k * F2 + n] : 0.f;
  }
  __syncthreads();
  int tx = t & 15, ty = t >> 4;
  int ms = tx * 4, ns = ty * 7;
  float acc[4][7];
#pragma unroll
  for (int i = 0; i < 4; i++)
#pragma unroll
    for (int j = 0; j < 7; j++) acc[i][j] = 0.f;
  for (int k = 0; k < F2; k++) {
    float a0 = As[(ms + 0) * A2PAD + k];
    float a1 = As[(ms + 1) * A2PAD + k];
    float a2 = As[(ms + 2) * A2PAD + k];
    float a3 = As[(ms + 3) * A2PAD + k];
    float b[7];
#pragma unroll
    for (int j = 0; j < 7; j++) b[j] = Ws[k * 112 + ns + j];
#pragma unroll
    for (int j = 0; j < 7; j++) {
      acc[0][j] += a0 * b[j];
      acc[1][j] += a1 * b[j];
      acc[2][j] += a2 * b[j];
      acc[3][j] += a3 * b[j];
    }
  }
  float b2n[7];
#pragma unroll
  for (int j = 0; j < 7; j++) {
    int n = ns + j;
    b2n[j] = (n < F2) ? b2[n] : 0.f;
  }
  int bmin = batch[m0];
  float pj[7];
#pragma unroll
  for (int j = 0; j < 7; j++) pj[j] = 0.f;
  int curb = -1;
#pragma unroll
  for (int i = 0; i < 4; i++) {
    int gm = m0 + ms + i;
    if (gm >= N_NODES) break;
    int b = batch[gm];
    if (b != curb) {
      if (curb >= 0) {
        int slot = curb - bmin;
        if (slot >= 0 && slot < 4) {
#pragma unroll
          for (int j = 0; j < 7; j++)
            if (ns + j < F2) atomicAdd(&psum[slot * 112 + ns + j], pj[j]);
        } else {
          float* pg = pooled + (size_t)curb * POOLW + HF;
#pragma unroll
          for (int j = 0; j < 7; j++)
            if (ns + j < F2) atomicAdd(&pg[ns + j], pj[j]);
        }
      }
      curb = b;
#pragma unroll
      for (int j = 0; j < 7; j++)
        pj[j] = (ns + j < F2) ? fmaxf(acc[i][j] + b2n[j], 0.f) : 0.f;
    } else {
#pragma unroll
      for (int j = 0; j < 7; j++)
        if (ns + j < F2) pj[j] += fmaxf(acc[i][j] + b2n[j], 0.f);
    }
  }
  if (curb >= 0) {
    int slot = curb - bmin;
    if (slot >= 0 && slot < 4) {
#pragma unroll
      for (int j = 0; j < 7; j++)
        if (ns + j < F2) atomicAdd(&psum[slot * 112 + ns + j], pj[j]);
    } else {
      float* pg = pooled + (size_t)curb * POOLW + HF;
#pragma unroll
      for (int j = 0; j < 7; j++)
        if (ns + j < F2) atomicAdd(&pg[ns + j], pj[j]);
    }
  }
  __syncthreads();
  for (int idx = t; idx < 4 * 112; idx += 256) {
    int slot = idx / 112, n = idx % 112;
    float v = psum[idx];
    int b = bmin + slot;
    if (n < F2 && b < BATCH && v != 0.f)
      atomicAdd(&pooled[(size_t)b * POOLW + HF + n], v);
  }
}

// ---------------------------------------------------------------------------
// EdgeConv v9: edge-contiguous tiles (uniform walk, no per-node tile padding
// or serial node advance). Per-block: U rows + edge->node map + rp in LDS;
// per-node max via monotonic-uint LDS atomicMax with adjacent-row merging;
// batch-slot pooled epilogue. V gathers prefetched 1 tile ahead, colidx 2.
// ---------------------------------------------------------------------------
#define ECH 25
#define EMAXE 1024
__global__ __launch_bounds__(256) void k_ec(
    const short* __restrict__ Ub, const short* __restrict__ Vb,
    const float* __restrict__ w2, const float* __restrict__ b2,
    const int* __restrict__ rp, const int* __restrict__ colidx,
    const int* __restrict__ batch, float* __restrict__ pooled) {
  const int t = threadIdx.x;
  const int lane = t & 63, wid = t >> 6;
  const int n16 = lane & 15, quad = lane >> 4;
  const int nt = (wid == 3) ? 1 : 2;   // u-tile 7 is all-pad

  const int i0 = blockIdx.x * ECH;
  const int iend = min(i0 + ECH, N_NODES);
  const int nn = iend - i0;

  __shared__ int rpL[ECH + 1];
  __shared__ int batL[ECH];
  __shared__ short Ul[ECH][128];
  __shared__ unsigned char earr[EMAXE];
  __shared__ unsigned nmax[ECH][128];
  __shared__ float psum[4][128];
  __shared__ short hs[2][16 * 16 * 8];

  short8 Bh[2][4];
  for (int tt = 0; tt < 2; tt++) {
    int ucol = (wid * 2 + tt) * 16 + n16;
    for (int kc = 0; kc < 4; kc++) {
      short8 vh;
#pragma unroll
      for (int jv = 0; jv < 8; jv++) {
        int kk = kc * 32 + quad * 8 + jv;
        float w = (ucol < F2 && kk < F2) ? w2[kk * F2 + ucol] : 0.f;
        vh[jv] = f2bf(w);
      }
      Bh[tt][kc] = vh;
    }
  }

  if (t <= nn) rpL[t] = rp[i0 + t];
  if (t < nn) batL[t] = batch[i0 + t];
  for (int idx = t; idx < nn * 128; idx += 256) {
    int n = idx >> 7, c = idx & 127;
    Ul[n][c] = Ub[(size_t)(i0 + n) * ECS + c];
    nmax[n][c] = 0u;
  }
  for (int idx = t; idx < 4 * 128; idx += 256) psum[idx >> 7][idx & 127] = 0.f;
  __syncthreads();

  const int base0 = rpL[0];
  const int eend = rpL[nn];
  const int ne = eend - base0;
  const int ntiles = (ne + 15) >> 4;

  // edge -> local node map (block edges are CSR-contiguous)
  for (int n = t; n < nn; n += 256) {
    int s0 = rpL[n] - base0;
    int s1 = min(rpL[n + 1] - base0, EMAXE);
    for (int e = s0; e < s1; e++) earr[e] = (unsigned char)n;
  }
  __syncthreads();

  auto nodeof = [&](int eo) -> int {
    if (eo < EMAXE) return earr[eo];
    int e = base0 + eo, lo = 0, hi = nn - 1;
    while (lo < hi) { int mid = (lo + hi + 1) >> 1; if (rpL[mid] <= e) lo = mid; else hi = mid - 1; }
    return lo;
  };

  union SU { short8 s; unsigned u[4]; };
  const int es = t & 15, kg = t >> 4;
  const int k0 = kg * 8;
  const int u0 = (wid * 2) * 16 + n16;
  const int u1 = (wid * 2 + 1) * 16 + n16;

  short8 pv8{}, pvN{};
  int node_cur = 0, nodeN = 0, s1 = 0;
  if (ntiles > 0) {
    int eo0 = min(es, ne - 1);
    int sc0 = colidx[base0 + eo0];
    pv8 = *(const short8*)(Vb + (size_t)sc0 * ECS + k0);
    node_cur = nodeof(eo0);
    int eo1 = min(16 + es, ne - 1);
    s1 = colidx[base0 + eo1];
  }
  int parity = 0;
  for (int tile = 0; tile < ntiles; ++tile, parity ^= 1) {
    // stage h = relu(U[dst] + V[src]) -> bf16 -> LDS
    short8 ul = *(const short8*)(&Ul[node_cur][k0]);
    SU w;
#pragma unroll
    for (int p = 0; p < 4; p++) {
      bool kv = (k0 + 2 * p) < F2;
      float h0 = kv ? fmaxf(bf2f(ul[2 * p])     + bf2f(pv8[2 * p]),     0.f) : 0.f;
      float h1 = kv ? fmaxf(bf2f(ul[2 * p + 1]) + bf2f(pv8[2 * p + 1]), 0.f) : 0.f;
      w.u[p] = pk2(h0, h1);
    }
    *(short8*)&hs[parity][(kg * 16 + es) * 8] = w.s;

    // prefetch: V for tile+1 (s1 fetched last iter), colidx for tile+2
    if (tile + 1 < ntiles) {
      pvN = *(const short8*)(Vb + (size_t)s1 * ECS + k0);
      nodeN = nodeof(min((tile + 1) * 16 + es, ne - 1));
      int eo2 = min((tile + 2) * 16 + es, ne - 1);
      s1 = colidx[base0 + eo2];
    }

    ldsbar();
    f32x4 a0 = {0.f, 0.f, 0.f, 0.f}, a1 = {0.f, 0.f, 0.f, 0.f};
#pragma unroll
    for (int kc = 0; kc < 4; kc++) {
      short8 af = *(const short8*)&hs[parity][((kc * 4 + quad) * 16 + n16) * 8];
      a0 = __builtin_amdgcn_mfma_f32_16x16x32_bf16(af, Bh[0][kc], a0, 0, 0, 0);
      if (nt > 1)
        a1 = __builtin_amdgcn_mfma_f32_16x16x32_bf16(af, Bh[1][kc], a1, 0, 0, 0);
    }
    // per-node max: merge adjacent same-node rows, then LDS atomicMax
    int nd0 = -1; float m0 = 0.f, m1 = 0.f;
#pragma unroll
    for (int r = 0; r < 4; r++) {
      int eo = tile * 16 + quad * 4 + r;
      if (eo < ne) {
        int nd = nodeof(eo);
        if (nd == nd0) { m0 = fmaxf(m0, a0[r]); m1 = fmaxf(m1, a1[r]); }
        else {
          if (nd0 >= 0) {
            atomicMax(&nmax[nd0][u0], fmap(m0));
            if (nt > 1) atomicMax(&nmax[nd0][u1], fmap(m1));
          }
          nd0 = nd; m0 = a0[r]; m1 = a1[r];
        }
      }
    }
    if (nd0 >= 0) {
      atomicMax(&nmax[nd0][u0], fmap(m0));
      if (nt > 1) atomicMax(&nmax[nd0][u1], fmap(m1));
    }
    pv8 = pvN; node_cur = nodeN;
  }

  __syncthreads();
  // epilogue: relu(max + b2), pool per batch slot
  int bmin = batL[0];
  for (int idx = t; idx < nn * 128; idx += 256) {
    int n = idx >> 7, u = idx & 127;
    unsigned m = nmax[n][u];
    if (u < F2 && m != 0u) {
      float o = fmaxf(funmap(m) + b2[u], 0.f);
      int slot = batL[n] - bmin;
      if (slot >= 0 && slot < 4) atomicAdd(&psum[slot][u], o);
      else atomicAdd(&pooled[(size_t)batL[n] * POOLW + HF + F2 + u], o);
    }
  }
  __syncthreads();
  for (int idx = t; idx < 4 * 128; idx += 256) {
    int slot = idx >> 7, u = idx & 127;
    float v = psum[slot][u];
    int b = bmin + slot;
    if (u < F2 && b < BATCH && v != 0.f)
      atomicAdd(&pooled[(size_t)b * POOLW + HF + F2 + u], v);
  }
}

// ---------------------------------------------------------------------------
// mean-pool divide (counts from sorted-batch boundaries)
// ---------------------------------------------------------------------------
__global__ void k_pooldiv(float* __restrict__ pooled, const int* __restrict__ start) {
  int t = blockIdx.x * blockDim.x + threadIdx.x;
  if (t >= BATCH * POOLW) return;
  int b = t / POOLW;
  float c = (float)(start[b + 1] - start[b]);
  pooled[t] /= fmaxf(c, 1.f);
}

// ---------------------------------------------------------------------------
// Per-graph heads: block g computes all three 2-layer MLPs -> cat[g][384]
// ---------------------------------------------------------------------------
__global__ __launch_bounds__(256) void k_heads(
    const float* __restrict__ pooled,
    const float* __restrict__ fg1_w, const float* __restrict__ fg1_b,
    const float* __restrict__ fg2_w, const float* __restrict__ fg2_b,
    const float* __restrict__ fg3_w, const float* __restrict__ fg3_b,
    const float* __restrict__ fg4_w, const float* __restrict__ fg4_b,
    const float* __restrict__ fg5_w, const float* __restrict__ fg5_b,
    const float* __restrict__ fg6_w, const float* __restrict__ fg6_b,
    float* __restrict__ cat) {
  int g = blockIdx.x, t = threadIdx.x;
  __shared__ float in[POOLW];
  __shared__ float mid[256];
  for (int idx = t; idx < POOLW; idx += 256) in[idx] = pooled[(size_t)g * POOLW + idx];
  __syncthreads();
  const float* w1s[3] = {fg1_w, fg3_w, fg5_w};
  const float* b1s[3] = {fg1_b, fg3_b, fg5_b};
  const float* w2s[3] = {fg2_w, fg4_w, fg6_w};
  const float* b2s[3] = {fg2_b, fg4_b, fg6_b};
  const int off[4] = {0, HF, HF + F2, POOLW};
  for (int br = 0; br < 3; br++) {
    int kin = off[br + 1] - off[br];
    const float* iv = &in[off[br]];
    float a = b1s[br][t];
    const float* W = w1s[br];
    for (int k = 0; k < kin; k++) a += iv[k] * W[k * 256 + t];
    mid[t] = fmaxf(a, 0.f);
    __syncthreads();
    if (t < 128) {
      float b = b2s[br][t];
      const float* W2 = w2s[br];
      for (int k = 0; k < 256; k++) b += mid[k] * W2[k * 128 + t];
      cat[(size_t)g * 384 + br * 128 + t] = fmaxf(b, 0.f);
    }
    __syncthreads();
  }
}

// ---------------------------------------------------------------------------
// Final MLP: cat[384] -> 128 -> 64 -> 1 sigmoid, block per graph
// ---------------------------------------------------------------------------
__global__ __launch_bounds__(256) void k_final(
    const float* __restrict__ cat,
    const float* __restrict__ fc1_w, const float* __restrict__ fc1_b,
    const float* __restrict__ fc2_w, const float* __restrict__ fc2_b,
    const float* __restrict__ out_w, const float* __restrict__ out_b,
    float* __restrict__ out) {
  int g = blockIdx.x, t = threadIdx.x;
  __shared__ float hin[384];
  __shared__ float h1[128];
  __shared__ float h2[64];
  for (int idx = t; idx < 384; idx += 256) hin[idx] = cat[(size_t)g * 384 + idx];
  __syncthreads();
  if (t < 128) {
    float a = fc1_b[t];
    for (int k = 0; k < 384; k++) a += hin[k] * fc1_w[k * 128 + t];
    h1[t] = fmaxf(a, 0.f);
  }
  __syncthreads();
  if (t < 64) {
    float a = fc2_b[t];
    for (int k = 0; k < 128; k++) a += h1[k] * fc2_w[k * 64 + t];
    h2[t] = fmaxf(a, 0.f);
  }
  __syncthreads();
  if (t == 0) {
    float a = out_b[0];
    for (int k = 0; k < 64; k++) a += h2[k] * out_w[k];
    out[g] = 1.f / (1.f + __expf(-a));
  }
}

// ---------------------------------------------------------------------------
extern "C" void kernel_launch(void* const* d_in, const int* in_sizes, int n_in,
                              void* d_out, int out_size, void* d_ws, size_t ws_size,
                              hipStream_t stream) {
  const float* x      = (const float*)d_in[0];
  const int*   ei     = (const int*)d_in[1];
  const int*   batch  = (const int*)d_in[2];
  const float* gat_w  = (const float*)d_in[3];
  const float* asrc   = (const float*)d_in[4];
  const float* adst   = (const float*)d_in[5];
  const float* gat_b  = (const float*)d_in[6];
  const float* gin_w1 = (const float*)d_in[7];
  const float* gin_b1 = (const float*)d_in[8];
  const float* gin_w2 = (const float*)d_in[9];
  const float* gin_b2 = (const float*)d_in[10];
  const float* ec_w1  = (const float*)d_in[11];
  const float* ec_b1  = (const float*)d_in[12];
  const float* ec_w2  = (const float*)d_in[13];
  const float* ec_b2  = (const float*)d_in[14];
  const float* fg1_w = (const float*)d_in[15]; const float* fg1_b = (const float*)d_in[16];
  const float* fg2_w = (const float*)d_in[17]; const float* fg2_b = (const float*)d_in[18];
  const float* fg3_w = (const float*)d_in[19]; const float* fg3_b = (const float*)d_in[20];
  const float* fg4_w = (const float*)d_in[21]; const float* fg4_b = (const float*)d_in[22];
  const float* fg5_w = (const float*)d_in[23]; const float* fg5_b = (const float*)d_in[24];
  const float* fg6_w = (const float*)d_in[25]; const float* fg6_b = (const float*)d_in[26];
  const float* fc1_w = (const float*)d_in[27]; const float* fc1_b = (const float*)d_in[28];
  const float* fc2_w = (const float*)d_in[29]; const float* fc2_b = (const float*)d_in[30];
  const float* out_w = (const float*)d_in[31]; const float* out_b = (const float*)d_in[32];
  float* out = (float*)d_out;

  char* ws = (char*)d_ws;
  size_t off = 0;
  auto alloc = [&](size_t bytes) -> void* {
    void* p = ws + off;
    off = (off + bytes + 255) & ~(size_t)255;
    return p;
  };
  // --- zero region (one memset): histP | pooled ---
  size_t zoff0 = off;
  int*   histP  = (int*)alloc((size_t)N_NODES * PSTR * sizeof(int));  // 6.4 MB padded bins
  float* pooled = (float*)alloc((size_t)BATCH * POOLW * sizeof(float));
  size_t zbytes = off - zoff0;
  // --- rest ---
  int*   rp     = (int*)alloc((N_NODES + 1) * sizeof(int));
  int*   start  = (int*)alloc((BATCH + 1) * sizeof(int));
  int*   bsum   = (int*)alloc(256 * sizeof(int));
  int*   colidx = (int*)alloc(N_EDGES * sizeof(int));
  short* xb     = (short*)alloc((size_t)N_NODES * 64 * sizeof(short));   // bf16 x rows, 128 B
  float* alS    = (float*)alloc((size_t)N_NODES * 4 * sizeof(float));
  float* alD    = (float*)alloc((size_t)N_NODES * 4 * sizeof(float));
  short* Ubuf   = (short*)alloc((size_t)N_NODES * ECS * sizeof(short));  // bf16, 256B rows
  short* Vbuf   = (short*)alloc((size_t)N_NODES * ECS * sizeof(short));  // bf16, 256B rows
  short* agg4   = (short*)alloc((size_t)N_NODES * HF * sizeof(short));   // GAT agg (bf16)
  float* agg    = (float*)alloc((size_t)N_NODES * FDIM * sizeof(float)); // GIN aggregate
  float* cAl    = (float*)alloc(FDIM * 8 * sizeof(float));
  float* Wp     = (float*)alloc((size_t)FDIM * NPK2 * sizeof(float));
  float* bpk    = (float*)alloc(NPK2 * sizeof(float));
  float* cat    = (float*)alloc((size_t)BATCH * 384 * sizeof(float));
  (void)ws_size; (void)in_sizes; (void)n_in; (void)out_size;
  // h1g (50000*106 f32 = 21.2 MB) aliases Ubuf+Vbuf (25.6 MB contiguous,
  // dead after k_ec; stream order serializes).
  float* h1g = (float*)Ubuf;

  hipMemsetAsync(ws + zoff0, 0, zbytes, stream);

  k_cal<<<1, 448, 0, stream>>>(gat_w, asrc, adst, cAl);
  k_prep<<<(FDIM * NPK2 + 255) / 256, 256, 0, stream>>>(ec_w1, ec_b1, cAl, Wp, bpk);
  k_gemm<<<((N_NODES + GM - 1) / GM) * 2, 256, 0, stream>>>(x, Wp, bpk,
                                                            xb, Ubuf, Vbuf, alS, alD);
  k_hist<<<(N_EDGES + 255) / 256, 256, 0, stream>>>(ei, histP);
  k_bnd<<<(N_NODES + 255) / 256, 256, 0, stream>>>(batch, start);
  k_scan1<<<SCAN_BLOCKS, 256, 0, stream>>>(histP, rp, bsum);
  k_scan2<<<1, 256, 0, stream>>>(bsum);
  k_scan3<<<SCAN_BLOCKS, 256, 0, stream>>>(bsum, rp, histP);
  k_scatter<<<(N_EDGES + 255) / 256, 256, 0, stream>>>(ei, histP, colidx);

  // fused GAT-aggregate + GIN-sum over one L2-resident bf16 x table
  k_gatgin<<<(N_NODES + GCH - 1) / GCH, 256, 0, stream>>>(xb, alS, alD, rp, colidx,
                                                          agg4, agg);
  k_ec<<<(N_NODES + ECH - 1) / ECH, 256, 0, stream>>>(Ubuf, Vbuf, ec_w2, ec_b2, rp, colidx, batch, pooled);
  // GAT per-head transform + relu + pool
  k_gtrans<<<(N_NODES + 63) / 64, 256, 0, stream>>>(agg4, gat_w, gat_b, batch, pooled);
  // GIN MLP (h1g aliases U/V, dead after k_ec)
  k_gin1<<<(N_NODES + 63) / 64, 256, 0, stream>>>(agg, gin_w1, gin_b1, h1g);
  k_gin2<<<(N_NODES + 63) / 64, 256, 0, stream>>>(h1g, gin_w2, gin_b2, batch, pooled);

  k_pooldiv<<<(BATCH * POOLW + 255) / 256, 256, 0, stream>>>(pooled, start);

  k_heads<<<BATCH, 256, 0, stream>>>(pooled, fg1_w, fg1_b, fg2_w, fg2_b, fg3_w, fg3_b,
                                     fg4_w, fg4_b, fg5_w, fg5_b, fg6_w, fg6_b, cat);
  k_final<<<BATCH, 256, 0, stream>>>(cat, fc1_w, fc1_b, fc2_w, fc2_b, out_w, out_b, out);
}

// Round 7
// 746.914 us; speedup vs baseline: 1.0231x; 1.0231x over previous
//
#include <hip/hip_runtime.h>
#include <hip/hip_bf16.h>
#include <math.h>

#define N_NODES 50000
#define N_EDGES 800000
#define FDIM 53
#define BATCH 128
#define HF 212   /* H*F */
#define F2 106   /* 2F  */
#define POOLW 424 /* 212+106+106 */
#define NPK2 220 /* 106 + 106 + 8: U | V | alS | alD */
#define PSTR 32  /* padded bin stride (ints) = 128 B: one L2 line per node */
#define ECS 128  /* U/V bf16 row stride (shorts) = 256 B = 4 L2 lines */

typedef __attribute__((ext_vector_type(8))) short short8;
typedef __attribute__((ext_vector_type(4))) float f32x4;

__device__ __forceinline__ float leaky02(float x){ return x >= 0.f ? x : 0.2f * x; }

__device__ __forceinline__ short f2bf(float x) {
  unsigned u = __float_as_uint(x);
  unsigned r = (u + 0x7fffu + ((u >> 16) & 1u)) >> 16;
  return (short)r;
}
__device__ __forceinline__ float bf2f(short b) {
  return __uint_as_float(((unsigned)(unsigned short)b) << 16);
}
// packed pair f32x2 -> bf16x2 (v_cvt_pk_bf16_f32, RNE)
__device__ __forceinline__ unsigned pk2(float a, float b) {
  union { __hip_bfloat162 h; unsigned u; } c;
  c.h = __float22bfloat162_rn(make_float2(a, b));
  return c.u;
}
// LDS-only barrier: waits lgkmcnt(0) (ds ops) but leaves global loads in flight
__device__ __forceinline__ void ldsbar() {
  __builtin_amdgcn_s_waitcnt(0xC07F);   // vmcnt(63) expcnt(7) lgkmcnt(0)
  __builtin_amdgcn_s_barrier();
}

// ---------------------------------------------------------------------------
// cAl[k*8 + sd*4 + h] = sum_f gat_w[k, h*53+f] * (sd? a_dst : a_src)[h,f]
// ---------------------------------------------------------------------------
__global__ void k_cal(const float* __restrict__ gat_w, const float* __restrict__ asrc,
                      const float* __restrict__ adst, float* __restrict__ cAl) {
  int t = threadIdx.x;
  if (t >= FDIM * 8) return;
  int k = t >> 3, r = t & 7, sd = r >> 2, h = r & 3;
  const float* av = sd ? adst : asrc;
  float acc = 0.f;
  for (int f = 0; f < FDIM; ++f) acc += gat_w[k * HF + h * FDIM + f] * av[h * FDIM + f];
  cAl[t] = acc;
}

// ---------------------------------------------------------------------------
// Pack Wp[53][220] = [W1top-W1bot | W1bot | cAl] and bias bp[220]
// ---------------------------------------------------------------------------
__global__ void k_prep(const float* __restrict__ ec_w1, const float* __restrict__ ec_b1,
                       const float* __restrict__ cAl,
                       float* __restrict__ Wp, float* __restrict__ bp) {
  int idx = blockIdx.x * blockDim.x + threadIdx.x;
  if (idx < FDIM * NPK2) {
    int k = idx / NPK2, j = idx % NPK2;
    float v;
    if (j < F2)            v = ec_w1[k * F2 + j] - ec_w1[(FDIM + k) * F2 + j];
    else if (j < 2 * F2)   v = ec_w1[(FDIM + k) * F2 + (j - F2)];
    else                   v = cAl[k * 8 + (j - 2 * F2)];
    Wp[idx] = v;
  }
  if (idx < NPK2) {
    bp[idx] = (idx < F2) ? ec_b1[idx] : 0.f;
  }
}

// ---------------------------------------------------------------------------
// Node-linear GEMM: x[50000x53] @ Wp[53x220] + bp -> U | V | alS | alD.
// Also emits xb (bf16 x rows, 64-short stride) during A-tile staging.
// ---------------------------------------------------------------------------
#define GM 64
#define GN 110
#define GNP 112
#define APAD 57
__global__ __launch_bounds__(256) void k_gemm(
    const float* __restrict__ x, const float* __restrict__ Wp, const float* __restrict__ bp,
    short* __restrict__ xb, short* __restrict__ Ub, short* __restrict__ Vb,
    float* __restrict__ alS, float* __restrict__ alD) {
  __shared__ float As[GM * APAD];
  __shared__ float Ws[FDIM * GNP];
  int mb = blockIdx.x >> 1, nc = blockIdx.x & 1;
  int m0 = mb * GM, n0 = nc * GN;
  int t = threadIdx.x;
  for (int idx = t; idx < GM * FDIM; idx += 256) {
    int m = idx / FDIM, k = idx % FDIM;
    int gm = m0 + m;
    float v = (gm < N_NODES) ? x[(size_t)gm * FDIM + k] : 0.f;
    As[m * APAD + k] = v;
    if (nc == 0 && gm < N_NODES) xb[(size_t)gm * 64 + k] = f2bf(v);
  }
  for (int idx = t; idx < FDIM * GNP; idx += 256) {
    int k = idx / GNP, n = idx % GNP;
    Ws[idx] = (n < GN) ? Wp[k * NPK2 + n0 + n] : 0.f;
  }
  __syncthreads();
  int tx = t & 15, ty = t >> 4;
  int ms = tx * 4, ns = ty * 7;
  float acc[4][7];
#pragma unroll
  for (int i = 0; i < 4; i++)
#pragma unroll
    for (int j = 0; j < 7; j++) acc[i][j] = 0.f;
  for (int k = 0; k < FDIM; k++) {
    float a0 = As[(ms + 0) * APAD + k];
    float a1 = As[(ms + 1) * APAD + k];
    float a2 = As[(ms + 2) * APAD + k];
    float a3 = As[(ms + 3) * APAD + k];
    float b[7];
#pragma unroll
    for (int j = 0; j < 7; j++) b[j] = Ws[k * GNP + ns + j];
#pragma unroll
    for (int j = 0; j < 7; j++) {
      acc[0][j] += a0 * b[j];
      acc[1][j] += a1 * b[j];
      acc[2][j] += a2 * b[j];
      acc[3][j] += a3 * b[j];
    }
  }
  float bj[7];
#pragma unroll
  for (int j = 0; j < 7; j++) {
    int g = n0 + ns + j;
    bj[j] = (g < NPK2) ? bp[g] : 0.f;
  }
#pragma unroll
  for (int i = 0; i < 4; i++) {
    int gm = m0 + ms + i;
    if (gm >= N_NODES) break;
#pragma unroll
    for (int j = 0; j < 7; j++) {
      int g = n0 + ns + j;
      float v = acc[i][j] + bj[j];
      if (g < F2)             Ub[(size_t)gm * ECS + g] = f2bf(v);
      else if (g < 2 * F2)    Vb[(size_t)gm * ECS + (g - F2)] = f2bf(v);
      else if (g < 2 * F2 + 4) alS[gm * 4 + (g - 2 * F2)] = v;
      else if (g < NPK2)      alD[gm * 4 + (g - 2 * F2 - 4)] = v;
    }
  }
}

// ---------------------------------------------------------------------------
// CSR build with L2-line-padded bins: hist -> scan (compacts to rp, turns
// padded slot into scatter cursor) -> scatter. Graph counts via sorted-batch
// boundary detection (no atomics).
// ---------------------------------------------------------------------------
#define SCAN_BLOCKS ((N_NODES + 255) / 256)

__global__ void k_hist(const int* __restrict__ ei, int* __restrict__ histP) {
  int t = blockIdx.x * blockDim.x + threadIdx.x;
  if (t < N_EDGES) atomicAdd(&histP[ei[N_EDGES + t] << 5], 1);
}

__global__ void k_bnd(const int* __restrict__ batch, int* __restrict__ start) {
  int t = blockIdx.x * blockDim.x + threadIdx.x;
  if (t >= N_NODES) return;
  int b = batch[t];
  if (t == 0)
    for (int g = 0; g <= b; g++) start[g] = 0;
  int bn = (t + 1 < N_NODES) ? batch[t + 1] : BATCH;
  for (int g = b + 1; g <= bn; g++) start[g] = t + 1;
}

__global__ __launch_bounds__(256) void k_scan1(const int* __restrict__ histP,
                                               int* __restrict__ rp, int* __restrict__ bsum) {
  __shared__ int buf[256];
  int tid = threadIdx.x;
  int idx = blockIdx.x * 256 + tid;
  int v = (idx < N_NODES) ? histP[idx << 5] : 0;
  buf[tid] = v;
  __syncthreads();
  for (int off = 1; off < 256; off <<= 1) {
    int t2 = (tid >= off) ? buf[tid - off] : 0;
    __syncthreads();
    buf[tid] += t2;
    __syncthreads();
  }
  if (idx < N_NODES) rp[idx] = buf[tid] - v;
  if (tid == 255) bsum[blockIdx.x] = buf[255];
}

__global__ __launch_bounds__(256) void k_scan2(int* __restrict__ bsum) {
  __shared__ int buf[256];
  int tid = threadIdx.x;
  int v = (tid < SCAN_BLOCKS) ? bsum[tid] : 0;
  buf[tid] = v;
  __syncthreads();
  for (int off = 1; off < 256; off <<= 1) {
    int t2 = (tid >= off) ? buf[tid - off] : 0;
    __syncthreads();
    buf[tid] += t2;
    __syncthreads();
  }
  if (tid < SCAN_BLOCKS) bsum[tid] = buf[tid] - v;
}

__global__ __launch_bounds__(256) void k_scan3(const int* __restrict__ bsum,
                                               int* __restrict__ rp, int* __restrict__ histP) {
  int idx = blockIdx.x * 256 + threadIdx.x;
  if (idx < N_NODES) {
    int o = rp[idx] + bsum[blockIdx.x];
    rp[idx] = o;
    histP[idx << 5] = o;   // becomes the (padded) scatter cursor
  }
  if (idx == 0) rp[N_NODES] = N_EDGES;
}

__global__ void k_scatter(const int* __restrict__ ei, int* __restrict__ histP,
                          int* __restrict__ colidx) {
  int e = blockIdx.x * blockDim.x + threadIdx.x;
  if (e >= N_EDGES) return;
  int d = ei[N_EDGES + e];
  int pos = atomicAdd(&histP[d << 5], 1);
  colidx[pos] = ei[e];
}

// ---------------------------------------------------------------------------
// Fused GAT-aggregate + GIN-sum: one edge walk gathering bf16 x rows (128 B
// line each, 6.4 MB table -> L2-resident). GAT uses aggregate-then-transform.
// ---------------------------------------------------------------------------
#define GCH 20
__global__ __launch_bounds__(256) void k_gatgin(
    const short* __restrict__ xb, const float* __restrict__ alS, const float* __restrict__ alD,
    const int* __restrict__ rp, const int* __restrict__ colidx,
    short* __restrict__ agg4, float* __restrict__ agg) {
  int wid = threadIdx.x >> 6, lane = threadIdx.x & 63;
  bool fa = lane < FDIM;
  int i0 = blockIdx.x * GCH;
  int iend = min(i0 + GCH, N_NODES);
  __shared__ int rpG[GCH + 1];
  {
    int t = threadIdx.x, nn = iend - i0;
    if (t <= nn) rpG[t] = rp[i0 + t];
  }
  __syncthreads();
  for (int i = i0 + wid; i < iend; i += 4) {
    int base = rpG[i - i0], deg = rpG[i - i0 + 1] - base;
    float aldi[4], exs[4];
#pragma unroll
    for (int h = 0; h < 4; h++) {
      aldi[h] = alD[i * 4 + h];
      exs[h] = __expf(leaky02(alS[i * 4 + h] + aldi[h]));   // self-loop term
    }
    float xiv = fa ? bf2f(xb[(size_t)i * 64 + lane]) : 0.f;
    float ag0 = exs[0] * xiv, ag1 = exs[1] * xiv, ag2 = exs[2] * xiv, ag3 = exs[3] * xiv;
    float ax = xiv;
    float zl[4] = {0.f, 0.f, 0.f, 0.f};

    for (int c0 = 0; c0 < deg; c0 += 64) {
      int cn = min(64, deg - c0);
      int s = 0;
      float ex0 = 0.f, ex1 = 0.f, ex2 = 0.f, ex3 = 0.f;
      if (lane < cn) {
        s = colidx[base + c0 + lane];
        ex0 = __expf(leaky02(alS[s * 4 + 0] + aldi[0]));
        ex1 = __expf(leaky02(alS[s * 4 + 1] + aldi[1]));
        ex2 = __expf(leaky02(alS[s * 4 + 2] + aldi[2]));
        ex3 = __expf(leaky02(alS[s * 4 + 3] + aldi[3]));
        zl[0] += ex0; zl[1] += ex1; zl[2] += ex2; zl[3] += ex3;
      }
      for (int jj = 0; jj < cn; jj += 4) {
        int sj[4]; float a0[4], a1[4], a2[4], a3[4]; bool vq[4];
#pragma unroll
        for (int q = 0; q < 4; q++) {
          int j2 = jj + q;
          int jc = (j2 < cn) ? j2 : (cn - 1);
          vq[q] = j2 < cn;
          sj[q] = __shfl(s, jc);
          a0[q] = vq[q] ? __shfl(ex0, jc) : 0.f;
          a1[q] = vq[q] ? __shfl(ex1, jc) : 0.f;
          a2[q] = vq[q] ? __shfl(ex2, jc) : 0.f;
          a3[q] = vq[q] ? __shfl(ex3, jc) : 0.f;
        }
        float xg[4];
#pragma unroll
        for (int q = 0; q < 4; q++)
          xg[q] = fa ? bf2f(xb[(size_t)sj[q] * 64 + lane]) : 0.f;
#pragma unroll
        for (int q = 0; q < 4; q++) {
          ag0 += a0[q] * xg[q];
          ag1 += a1[q] * xg[q];
          ag2 += a2[q] * xg[q];
          ag3 += a3[q] * xg[q];
          ax += vq[q] ? xg[q] : 0.f;
        }
      }
    }
#pragma unroll
    for (int off = 32; off >= 1; off >>= 1)
#pragma unroll
      for (int h = 0; h < 4; h++) zl[h] += __shfl_xor(zl[h], off);
    if (fa) {
      float z0 = zl[0] + exs[0] + 1e-16f;
      float z1 = zl[1] + exs[1] + 1e-16f;
      float z2 = zl[2] + exs[2] + 1e-16f;
      float z3 = zl[3] + exs[3] + 1e-16f;
      short* ar = agg4 + (size_t)i * HF;
      ar[0 * FDIM + lane] = f2bf(ag0 / z0);
      ar[1 * FDIM + lane] = f2bf(ag1 / z1);
      ar[2 * FDIM + lane] = f2bf(ag2 / z2);
      ar[3 * FDIM + lane] = f2bf(ag3 / z3);
      agg[(size_t)i * FDIM + lane] = ax;
    }
  }
}

// ---------------------------------------------------------------------------
// GAT transform: grouped (per-head 53x53) GEMM + relu + pooled accumulation
// ---------------------------------------------------------------------------
#define TCOLS 224   /* 4 heads x 56 padded cols */
#define A4S 217     /* As row stride in shorts (odd -> conflict-free) */
__global__ __launch_bounds__(256) void k_gtrans(
    const short* __restrict__ agg4, const float* __restrict__ gat_w,
    const float* __restrict__ bias, const int* __restrict__ batch,
    float* __restrict__ pooled) {
  __shared__ short As[64 * A4S];
  __shared__ float Bs[FDIM * TCOLS];
  __shared__ float psum[4 * TCOLS];
  int m0 = blockIdx.x * 64;
  int t = threadIdx.x;
  for (int idx = t; idx < 4 * TCOLS; idx += 256) psum[idx] = 0.f;
  for (int idx = t; idx < 64 * HF; idx += 256) {
    int m = idx / HF, c = idx % HF;
    int gm = m0 + m;
    As[m * A4S + c] = (gm < N_NODES) ? agg4[(size_t)gm * HF + c] : (short)0;
  }
  for (int idx = t; idx < FDIM * TCOLS; idx += 256) {
    int k = idx / TCOLS, c = idx % TCOLS;
    int h = c / 56, jn = c % 56;
    Bs[idx] = (jn < FDIM) ? gat_w[k * HF + h * FDIM + jn] : 0.f;
  }
  __syncthreads();
  int tx = t & 15, ty = t >> 4;
  int ms = tx * 4, ns = ty * 14;
  int hh = ty >> 2;
  int jnb = (ty & 3) * 14;
  float acc[4][14];
#pragma unroll
  for (int i = 0; i < 4; i++)
#pragma unroll
    for (int j = 0; j < 14; j++) acc[i][j] = 0.f;
  for (int k = 0; k < FDIM; k++) {
    float a0 = bf2f(As[(ms + 0) * A4S + hh * FDIM + k]);
    float a1 = bf2f(As[(ms + 1) * A4S + hh * FDIM + k]);
    float a2 = bf2f(As[(ms + 2) * A4S + hh * FDIM + k]);
    float a3 = bf2f(As[(ms + 3) * A4S + hh * FDIM + k]);
    float b[14];
#pragma unroll
    for (int j = 0; j < 14; j++) b[j] = Bs[k * TCOLS + ns + j];
#pragma unroll
    for (int j = 0; j < 14; j++) {
      acc[0][j] += a0 * b[j];
      acc[1][j] += a1 * b[j];
      acc[2][j] += a2 * b[j];
      acc[3][j] += a3 * b[j];
    }
  }
  float bj[14]; bool jv[14];
#pragma unroll
  for (int j = 0; j < 14; j++) {
    jv[j] = (jnb + j) < FDIM;
    bj[j] = jv[j] ? bias[hh * FDIM + jnb + j] : 0.f;
  }
  int bmin = batch[m0];
  float pj[14];
#pragma unroll
  for (int j = 0; j < 14; j++) pj[j] = 0.f;
  int curb = -1;
#pragma unroll
  for (int i = 0; i < 4; i++) {
    int gm = m0 + ms + i;
    if (gm >= N_NODES) break;
    int b = batch[gm];
    if (b != curb) {
      if (curb >= 0) {
        int slot = curb - bmin;
        if (slot >= 0 && slot < 4) {
#pragma unroll
          for (int j = 0; j < 14; j++)
            if (jv[j]) atomicAdd(&psum[slot * TCOLS + ns + j], pj[j]);
        } else {
          float* pg = pooled + (size_t)curb * POOLW;
#pragma unroll
          for (int j = 0; j < 14; j++)
            if (jv[j]) atomicAdd(&pg[hh * FDIM + jnb + j], pj[j]);
        }
      }
      curb = b;
#pragma unroll
      for (int j = 0; j < 14; j++)
        pj[j] = jv[j] ? fmaxf(acc[i][j] + bj[j], 0.f) : 0.f;
    } else {
#pragma unroll
      for (int j = 0; j < 14; j++)
        if (jv[j]) pj[j] += fmaxf(acc[i][j] + bj[j], 0.f);
    }
  }
  if (curb >= 0) {
    int slot = curb - bmin;
    if (slot >= 0 && slot < 4) {
#pragma unroll
      for (int j = 0; j < 14; j++)
        if (jv[j]) atomicAdd(&psum[slot * TCOLS + ns + j], pj[j]);
    } else {
      float* pg = pooled + (size_t)curb * POOLW;
#pragma unroll
      for (int j = 0; j < 14; j++)
        if (jv[j]) atomicAdd(&pg[hh * FDIM + jnb + j], pj[j]);
    }
  }
  __syncthreads();
  for (int idx = t; idx < 4 * TCOLS; idx += 256) {
    int slot = idx / TCOLS, c = idx % TCOLS;
    int h = c / 56, jn = c % 56;
    float v = psum[idx];
    int b = bmin + slot;
    if (jn < FDIM && b < BATCH && v != 0.f)
      atomicAdd(&pooled[(size_t)b * POOLW + h * FDIM + jn], v);
  }
}

// ---------------------------------------------------------------------------
// GIN (2): h1g = relu(agg @ w1 + b1)
// ---------------------------------------------------------------------------
__global__ __launch_bounds__(256) void k_gin1(
    const float* __restrict__ agg, const float* __restrict__ w1, const float* __restrict__ b1,
    float* __restrict__ h1g) {
  __shared__ float As[64 * APAD];
  __shared__ float Ws[FDIM * 112];
  int m0 = blockIdx.x * 64;
  int t = threadIdx.x;
  for (int idx = t; idx < 64 * FDIM; idx += 256) {
    int m = idx / FDIM, k = idx % FDIM;
    int gm = m0 + m;
    As[m * APAD + k] = (gm < N_NODES) ? agg[(size_t)gm * FDIM + k] : 0.f;
  }
  for (int idx = t; idx < FDIM * 112; idx += 256) {
    int k = idx / 112, n = idx % 112;
    Ws[idx] = (n < F2) ? w1[k * F2 + n] : 0.f;
  }
  __syncthreads();
  int tx = t & 15, ty = t >> 4;
  int ms = tx * 4, ns = ty * 7;
  float acc[4][7];
#pragma unroll
  for (int i = 0; i < 4; i++)
#pragma unroll
    for (int j = 0; j < 7; j++) acc[i][j] = 0.f;
  for (int k = 0; k < FDIM; k++) {
    float a0 = As[(ms + 0) * APAD + k];
    float a1 = As[(ms + 1) * APAD + k];
    float a2 = As[(ms + 2) * APAD + k];
    float a3 = As[(ms + 3) * APAD + k];
    float b[7];
#pragma unroll
    for (int j = 0; j < 7; j++) b[j] = Ws[k * 112 + ns + j];
#pragma unroll
    for (int j = 0; j < 7; j++) {
      acc[0][j] += a0 * b[j];
      acc[1][j] += a1 * b[j];
      acc[2][j] += a2 * b[j];
      acc[3][j] += a3 * b[j];
    }
  }
#pragma unroll
  for (int i = 0; i < 4; i++) {
    int gm = m0 + ms + i;
    if (gm >= N_NODES) break;
#pragma unroll
    for (int j = 0; j < 7; j++) {
      int n = ns + j;
      if (n < F2) h1g[(size_t)gm * F2 + n] = fmaxf(acc[i][j] + b1[n], 0.f);
    }
  }
}

// ---------------------------------------------------------------------------
// GIN (3): h2 = relu(h1g @ w2 + b2) + pooled accumulation (LDS psum)
// ---------------------------------------------------------------------------
#define A2PAD 111
__global__ __launch_bounds__(256) void k_gin2(
    const float* __restrict__ h1g, const float* __restrict__ w2, const float* __restrict__ b2,
    const int* __restrict__ batch, float* __restrict__ pooled) {
  __shared__ float As[64 * A2PAD];
  __shared__ float Ws[F2 * 112];
  __shared__ float psum[4 * 112];
  int m0 = blockIdx.x * 64;
  int t = threadIdx.x;
  for (int idx = t; idx < 4 * 112; idx += 256) psum[idx] = 0.f;
  for (int idx = t; idx < 64 * F2; idx += 256) {
    int m = idx / F2, k = idx % F2;
    int gm = m0 + m;
    As[m * A2PAD + k] = (gm < N_NODES) ? h1g[(size_t)gm * F2 + k] : 0.f;
  }
  for (int idx = t; idx < F2 * 112; idx += 256) {
    int k = idx / 112, n = idx % 112;
    Ws[idx] = (n < F2) ? w2[k * F2 + n] : 0.f;
  }
  __syncthreads();
  int tx = t & 15, ty = t >> 4;
  int ms = tx * 4, ns = ty * 7;
  float acc[4][7];
#pragma unroll
  for (int i = 0; i < 4; i++)
#pragma unroll
    for (int j = 0; j < 7; j++) acc[i][j] = 0.f;
  for (int k = 0; k < F2; k++) {
    float a0 = As[(ms + 0) * A2PAD + k];
    float a1 = As[(ms + 1) * A2PAD + k];
    float a2 = As[(ms + 2) * A2PAD + k];
    float a3 = As[(ms + 3) * A2PAD + k];
    float b[7];
#pragma unroll
    for (int j = 0; j < 7; j++) b[j] = Ws[k * 112 + ns + j];
#pragma unroll
    for (int j = 0; j < 7; j++) {
      acc[0][j] += a0 * b[j];
      acc[1][j] += a1 * b[j];
      acc[2][j] += a2 * b[j];
      acc[3][j] += a3 * b[j];
    }
  }
  float b2n[7];
#pragma unroll
  for (int j = 0; j < 7; j++) {
    int n = ns + j;
    b2n[j] = (n < F2) ? b2[n] : 0.f;
  }
  int bmin = batch[m0];
  float pj[7];
#pragma unroll
  for (int j = 0; j < 7; j++) pj[j] = 0.f;
  int curb = -1;
#pragma unroll
  for (int i = 0; i < 4; i++) {
    int gm = m0 + ms + i;
    if (gm >= N_NODES) break;
    int b = batch[gm];
    if (b != curb) {
      if (curb >= 0) {
        int slot = curb - bmin;
        if (slot >= 0 && slot < 4) {
#pragma unroll
          for (int j = 0; j < 7; j++)
            if (ns + j < F2) atomicAdd(&psum[slot * 112 + ns + j], pj[j]);
        } else {
          float* pg = pooled + (size_t)curb * POOLW + HF;
#pragma unroll
          for (int j = 0; j < 7; j++)
            if (ns + j < F2) atomicAdd(&pg[ns + j], pj[j]);
        }
      }
      curb = b;
#pragma unroll
      for (int j = 0; j < 7; j++)
        pj[j] = (ns + j < F2) ? fmaxf(acc[i][j] + b2n[j], 0.f) : 0.f;
    } else {
#pragma unroll
      for (int j = 0; j < 7; j++)
        if (ns + j < F2) pj[j] += fmaxf(acc[i][j] + b2n[j], 0.f);
    }
  }
  if (curb >= 0) {
    int slot = curb - bmin;
    if (slot >= 0 && slot < 4) {
#pragma unroll
      for (int j = 0; j < 7; j++)
        if (ns + j < F2) atomicAdd(&psum[slot * 112 + ns + j], pj[j]);
    } else {
      float* pg = pooled + (size_t)curb * POOLW + HF;
#pragma unroll
      for (int j = 0; j < 7; j++)
        if (ns + j < F2) atomicAdd(&pg[ns + j], pj[j]);
    }
  }
  __syncthreads();
  for (int idx = t; idx < 4 * 112; idx += 256) {
    int slot = idx / 112, n = idx % 112;
    float v = psum[idx];
    int b = bmin + slot;
    if (n < F2 && b < BATCH && v != 0.f)
      atomicAdd(&pooled[(size_t)b * POOLW + HF + n], v);
  }
}

// ---------------------------------------------------------------------------
// EdgeConv v11: v8 structure (node-granular tiles, register max, no LDS
// atomics) with a 2-tile-deep gather pipeline: 4-slot coordinate queue;
// V/U rows for tile T+2 issued while T is staged (2 iterations in flight),
// colidx fetched at T+3. Double-buffered LDS, lgkmcnt-only barrier.
// ---------------------------------------------------------------------------
#define ECH 25
__global__ __launch_bounds__(256) void k_ec(
    const short* __restrict__ Ub, const short* __restrict__ Vb,
    const float* __restrict__ w2, const float* __restrict__ b2,
    const int* __restrict__ rp, const int* __restrict__ colidx,
    const int* __restrict__ batch, float* __restrict__ pooled) {
  const int t = threadIdx.x;
  const int lane = t & 63, wid = t >> 6;
  const int n16 = lane & 15, quad = lane >> 4;
  const int nt = (wid == 3) ? 1 : 2;   // u-tile 7 is all-pad

  const int i0 = blockIdx.x * ECH;
  const int iend = min(i0 + ECH, N_NODES);
  const int nn = iend - i0;

  __shared__ int rpL[ECH + 1];
  __shared__ int batL[ECH];

  short8 Bh[2][4];
  for (int tt = 0; tt < 2; tt++) {
    int ucol = (wid * 2 + tt) * 16 + n16;
    for (int kc = 0; kc < 4; kc++) {
      short8 vh;
#pragma unroll
      for (int jv = 0; jv < 8; jv++) {
        int kk = kc * 32 + quad * 8 + jv;
        float w = (ucol < F2 && kk < F2) ? w2[kk * F2 + ucol] : 0.f;
        vh[jv] = f2bf(w);
      }
      Bh[tt][kc] = vh;
    }
  }
  float b2v[2];
#pragma unroll
  for (int tt = 0; tt < 2; tt++) {
    int u = (wid * 2 + tt) * 16 + n16;
    b2v[tt] = (u < F2) ? b2[u] : 0.f;
  }

  if (t <= nn) rpL[t] = rp[i0 + t];
  if (t < nn) batL[t] = batch[i0 + t];
  __syncthreads();

  __shared__ short hs[2][16 * 16 * 8];
  union SU { short8 s; unsigned u[4]; };
  const int es = t & 15, kg = t >> 4;
  const int k0 = kg * 8;

  float sm0 = 0.f, sm1 = 0.f;
  int curb = -1;
  const int u0 = (wid * 2) * 16 + n16;
  const int u1 = (wid * 2 + 1) * 16 + n16;

  // tile walk: (node, tile-in-node, base, deg) -> next
  auto advance = [&](int& ii, int& ttb, int& bb, int& dd) -> bool {
    ttb++;
    if (ttb * 16 < dd) return true;
    ttb = 0;
    for (ii = ii + 1; ii < iend; ii++) {
      bb = rpL[ii - i0]; dd = rpL[ii - i0 + 1] - bb;
      if (dd > 0) return true;
    }
    return false;
  };

  // slot 0 = current tile
  int i_0 = i0, tb_0 = 0, ba_0 = 0, dg_0 = 0;
  bool h_0 = false;
  for (; i_0 < iend; i_0++) {
    ba_0 = rpL[i_0 - i0]; dg_0 = rpL[i_0 - i0 + 1] - ba_0;
    if (dg_0 > 0) { h_0 = true; break; }
  }
  int i_1 = i_0, tb_1 = tb_0, ba_1 = ba_0, dg_1 = dg_0; bool h_1 = false;
  int i_2 = 0, tb_2 = 0, ba_2 = 0, dg_2 = 0; bool h_2 = false;
  int i_3 = 0, tb_3 = 0, ba_3 = 0, dg_3 = 0; bool h_3 = false;
  short8 pvA{}, pvB{}, pvC{}, puA{}, puB{}, puC{};
  int s2 = 0;
  if (h_0) {
    h_1 = advance(i_1, tb_1, ba_1, dg_1);
    i_2 = i_1; tb_2 = tb_1; ba_2 = ba_1; dg_2 = dg_1;
    if (h_1) h_2 = advance(i_2, tb_2, ba_2, dg_2);
    i_3 = i_2; tb_3 = tb_2; ba_3 = ba_2; dg_3 = dg_2;
    if (h_2) h_3 = advance(i_3, tb_3, ba_3, dg_3);

    int sA = colidx[ba_0 + ((es < dg_0) ? es : 0)];
    pvA = *(const short8*)(Vb + (size_t)sA * ECS + k0);
    puA = *(const short8*)(Ub + (size_t)i_0 * ECS + k0);
    if (h_1) {
      int eg = tb_1 * 16 + es;
      int sB = colidx[ba_1 + ((eg < dg_1) ? eg : 0)];
      pvB = *(const short8*)(Vb + (size_t)sB * ECS + k0);
      if (tb_1 == 0) puB = *(const short8*)(Ub + (size_t)i_1 * ECS + k0);
    }
    if (h_2) {
      int eg = tb_2 * 16 + es;
      s2 = colidx[ba_2 + ((eg < dg_2) ? eg : 0)];
    }
  }

  float Uc[8];
  float vmax0 = -1e30f, vmax1 = -1e30f;
  int parity = 0;
  while (h_0) {
    if (tb_0 == 0) {
#pragma unroll
      for (int j = 0; j < 8; j++) Uc[j] = bf2f(puA[j]);
    }
    SU w;
#pragma unroll
    for (int p = 0; p < 4; p++) {
      bool kv = (k0 + 2 * p) < F2;
      float h0v = kv ? fmaxf(Uc[2 * p]     + bf2f(pvA[2 * p]),     0.f) : 0.f;
      float h1v = kv ? fmaxf(Uc[2 * p + 1] + bf2f(pvA[2 * p + 1]), 0.f) : 0.f;
      w.u[p] = pk2(h0v, h1v);
    }
    *(short8*)&hs[parity][(kg * 16 + es) * 8] = w.s;

    // issue V/U for tile T+2 (s2 loaded last iter), colidx for T+3
    int s3 = 0;
    if (h_2) {
      pvC = *(const short8*)(Vb + (size_t)s2 * ECS + k0);
      if (tb_2 == 0) puC = *(const short8*)(Ub + (size_t)i_2 * ECS + k0);
      if (h_3) {
        int eg = tb_3 * 16 + es;
        s3 = colidx[ba_3 + ((eg < dg_3) ? eg : 0)];
      }
    }

    ldsbar();
    f32x4 a0 = {0.f, 0.f, 0.f, 0.f}, a1 = {0.f, 0.f, 0.f, 0.f};
#pragma unroll
    for (int kc = 0; kc < 4; kc++) {
      short8 af = *(const short8*)&hs[parity][((kc * 4 + quad) * 16 + n16) * 8];
      a0 = __builtin_amdgcn_mfma_f32_16x16x32_bf16(af, Bh[0][kc], a0, 0, 0, 0);
      if (nt > 1)
        a1 = __builtin_amdgcn_mfma_f32_16x16x32_bf16(af, Bh[1][kc], a1, 0, 0, 0);
    }
#pragma unroll
    for (int r = 0; r < 4; r++) {
      int er = tb_0 * 16 + quad * 4 + r;
      if (er < dg_0) { vmax0 = fmaxf(vmax0, a0[r]); vmax1 = fmaxf(vmax1, a1[r]); }
    }
    if (!h_1 || i_1 != i_0) {
      // node finishes with this tile: cross-quad reduce deferred to here
      vmax0 = fmaxf(vmax0, __shfl_xor(vmax0, 16));
      vmax0 = fmaxf(vmax0, __shfl_xor(vmax0, 32));
      vmax1 = fmaxf(vmax1, __shfl_xor(vmax1, 16));
      vmax1 = fmaxf(vmax1, __shfl_xor(vmax1, 32));
      float o0 = fmaxf(vmax0 + b2v[0], 0.f);
      float o1 = fmaxf(vmax1 + b2v[1], 0.f);
      int b = batL[i_0 - i0];
      if (b != curb) {
        if (curb >= 0 && quad == 0) {
          float* pg = pooled + (size_t)curb * POOLW + HF + F2;
          if (u0 < F2) atomicAdd(&pg[u0], sm0);
          if (nt > 1 && u1 < F2) atomicAdd(&pg[u1], sm1);
        }
        curb = b; sm0 = o0; sm1 = o1;
      } else {
        sm0 += o0; sm1 += o1;
      }
      vmax0 = -1e30f; vmax1 = -1e30f;
    }
    // shift pipeline
    i_0 = i_1; tb_0 = tb_1; ba_0 = ba_1; dg_0 = dg_1; h_0 = h_1;
    i_1 = i_2; tb_1 = tb_2; ba_1 = ba_2; dg_1 = dg_2; h_1 = h_2;
    i_2 = i_3; tb_2 = tb_3; ba_2 = ba_3; dg_2 = dg_3; h_2 = h_3;
    if (h_3) h_3 = advance(i_3, tb_3, ba_3, dg_3);
    pvA = pvB; pvB = pvC;
    puA = puB; puB = puC;
    s2 = s3;
    parity ^= 1;
  }
  if (curb >= 0 && quad == 0) {
    float* pg = pooled + (size_t)curb * POOLW + HF + F2;
    if (u0 < F2) atomicAdd(&pg[u0], sm0);
    if (nt > 1 && u1 < F2) atomicAdd(&pg[u1], sm1);
  }
}

// ---------------------------------------------------------------------------
// mean-pool divide (counts from sorted-batch boundaries)
// ---------------------------------------------------------------------------
__global__ void k_pooldiv(float* __restrict__ pooled, const int* __restrict__ start) {
  int t = blockIdx.x * blockDim.x + threadIdx.x;
  if (t >= BATCH * POOLW) return;
  int b = t / POOLW;
  float c = (float)(start[b + 1] - start[b]);
  pooled[t] /= fmaxf(c, 1.f);
}

// ---------------------------------------------------------------------------
// Per-graph heads: block g computes all three 2-layer MLPs -> cat[g][384]
// ---------------------------------------------------------------------------
__global__ __launch_bounds__(256) void k_heads(
    const float* __restrict__ pooled,
    const float* __restrict__ fg1_w, const float* __restrict__ fg1_b,
    const float* __restrict__ fg2_w, const float* __restrict__ fg2_b,
    const float* __restrict__ fg3_w, const float* __restrict__ fg3_b,
    const float* __restrict__ fg4_w, const float* __restrict__ fg4_b,
    const float* __restrict__ fg5_w, const float* __restrict__ fg5_b,
    const float* __restrict__ fg6_w, const float* __restrict__ fg6_b,
    float* __restrict__ cat) {
  int g = blockIdx.x, t = threadIdx.x;
  __shared__ float in[POOLW];
  __shared__ float mid[256];
  for (int idx = t; idx < POOLW; idx += 256) in[idx] = pooled[(size_t)g * POOLW + idx];
  __syncthreads();
  const float* w1s[3] = {fg1_w, fg3_w, fg5_w};
  const float* b1s[3] = {fg1_b, fg3_b, fg5_b};
  const float* w2s[3] = {fg2_w, fg4_w, fg6_w};
  const float* b2s[3] = {fg2_b, fg4_b, fg6_b};
  const int off[4] = {0, HF, HF + F2, POOLW};
  for (int br = 0; br < 3; br++) {
    int kin = off[br + 1] - off[br];
    const float* iv = &in[off[br]];
    float a = b1s[br][t];
    const float* W = w1s[br];
    for (int k = 0; k < kin; k++) a += iv[k] * W[k * 256 + t];
    mid[t] = fmaxf(a, 0.f);
    __syncthreads();
    if (t < 128) {
      float b = b2s[br][t];
      const float* W2 = w2s[br];
      for (int k = 0; k < 256; k++) b += mid[k] * W2[k * 128 + t];
      cat[(size_t)g * 384 + br * 128 + t] = fmaxf(b, 0.f);
    }
    __syncthreads();
  }
}

// ---------------------------------------------------------------------------
// Final MLP: cat[384] -> 128 -> 64 -> 1 sigmoid, block per graph
// ---------------------------------------------------------------------------
__global__ __launch_bounds__(256) void k_final(
    const float* __restrict__ cat,
    const float* __restrict__ fc1_w, const float* __restrict__ fc1_b,
    const float* __restrict__ fc2_w, const float* __restrict__ fc2_b,
    const float* __restrict__ out_w, const float* __restrict__ out_b,
    float* __restrict__ out) {
  int g = blockIdx.x, t = threadIdx.x;
  __shared__ float hin[384];
  __shared__ float h1[128];
  __shared__ float h2[64];
  for (int idx = t; idx < 384; idx += 256) hin[idx] = cat[(size_t)g * 384 + idx];
  __syncthreads();
  if (t < 128) {
    float a = fc1_b[t];
    for (int k = 0; k < 384; k++) a += hin[k] * fc1_w[k * 128 + t];
    h1[t] = fmaxf(a, 0.f);
  }
  __syncthreads();
  if (t < 64) {
    float a = fc2_b[t];
    for (int k = 0; k < 128; k++) a += h1[k] * fc2_w[k * 64 + t];
    h2[t] = fmaxf(a, 0.f);
  }
  __syncthreads();
  if (t == 0) {
    float a = out_b[0];
    for (int k = 0; k < 64; k++) a += h2[k] * out_w[k];
    out[g] = 1.f / (1.f + __expf(-a));
  }
}

// ---------------------------------------------------------------------------
extern "C" void kernel_launch(void* const* d_in, const int* in_sizes, int n_in,
                              void* d_out, int out_size, void* d_ws, size_t ws_size,
                              hipStream_t stream) {
  const float* x      = (const float*)d_in[0];
  const int*   ei     = (const int*)d_in[1];
  const int*   batch  = (const int*)d_in[2];
  const float* gat_w  = (const float*)d_in[3];
  const float* asrc   = (const float*)d_in[4];
  const float* adst   = (const float*)d_in[5];
  const float* gat_b  = (const float*)d_in[6];
  const float* gin_w1 = (const float*)d_in[7];
  const float* gin_b1 = (const float*)d_in[8];
  const float* gin_w2 = (const float*)d_in[9];
  const float* gin_b2 = (const float*)d_in[10];
  const float* ec_w1  = (const float*)d_in[11];
  const float* ec_b1  = (const float*)d_in[12];
  const float* ec_w2  = (const float*)d_in[13];
  const float* ec_b2  = (const float*)d_in[14];
  const float* fg1_w = (const float*)d_in[15]; const float* fg1_b = (const float*)d_in[16];
  const float* fg2_w = (const float*)d_in[17]; const float* fg2_b = (const float*)d_in[18];
  const float* fg3_w = (const float*)d_in[19]; const float* fg3_b = (const float*)d_in[20];
  const float* fg4_w = (const float*)d_in[21]; const float* fg4_b = (const float*)d_in[22];
  const float* fg5_w = (const float*)d_in[23]; const float* fg5_b = (const float*)d_in[24];
  const float* fg6_w = (const float*)d_in[25]; const float* fg6_b = (const float*)d_in[26];
  const float* fc1_w = (const float*)d_in[27]; const float* fc1_b = (const float*)d_in[28];
  const float* fc2_w = (const float*)d_in[29]; const float* fc2_b = (const float*)d_in[30];
  const float* out_w = (const float*)d_in[31]; const float* out_b = (const float*)d_in[32];
  float* out = (float*)d_out;

  char* ws = (char*)d_ws;
  size_t off = 0;
  auto alloc = [&](size_t bytes) -> void* {
    void* p = ws + off;
    off = (off + bytes + 255) & ~(size_t)255;
    return p;
  };
  // --- zero region (one memset): histP | pooled ---
  size_t zoff0 = off;
  int*   histP  = (int*)alloc((size_t)N_NODES * PSTR * sizeof(int));  // 6.4 MB padded bins
  float* pooled = (float*)alloc((size_t)BATCH * POOLW * sizeof(float));
  size_t zbytes = off - zoff0;
  // --- rest ---
  int*   rp     = (int*)alloc((N_NODES + 1) * sizeof(int));
  int*   start  = (int*)alloc((BATCH + 1) * sizeof(int));
  int*   bsum   = (int*)alloc(256 * sizeof(int));
  int*   colidx = (int*)alloc(N_EDGES * sizeof(int));
  short* xb     = (short*)alloc((size_t)N_NODES * 64 * sizeof(short));   // bf16 x rows, 128 B
  float* alS    = (float*)alloc((size_t)N_NODES * 4 * sizeof(float));
  float* alD    = (float*)alloc((size_t)N_NODES * 4 * sizeof(float));
  short* Ubuf   = (short*)alloc((size_t)N_NODES * ECS * sizeof(short));  // bf16, 256B rows
  short* Vbuf   = (short*)alloc((size_t)N_NODES * ECS * sizeof(short));  // bf16, 256B rows
  short* agg4   = (short*)alloc((size_t)N_NODES * HF * sizeof(short));   // GAT agg (bf16)
  float* agg    = (float*)alloc((size_t)N_NODES * FDIM * sizeof(float)); // GIN aggregate
  float* cAl    = (float*)alloc(FDIM * 8 * sizeof(float));
  float* Wp     = (float*)alloc((size_t)FDIM * NPK2 * sizeof(float));
  float* bpk    = (float*)alloc(NPK2 * sizeof(float));
  float* cat    = (float*)alloc((size_t)BATCH * 384 * sizeof(float));
  (void)ws_size; (void)in_sizes; (void)n_in; (void)out_size;
  // h1g (50000*106 f32 = 21.2 MB) aliases Ubuf+Vbuf (25.6 MB contiguous,
  // dead after k_ec; stream order serializes).
  float* h1g = (float*)Ubuf;

  hipMemsetAsync(ws + zoff0, 0, zbytes, stream);

  k_cal<<<1, 448, 0, stream>>>(gat_w, asrc, adst, cAl);
  k_prep<<<(FDIM * NPK2 + 255) / 256, 256, 0, stream>>>(ec_w1, ec_b1, cAl, Wp, bpk);
  k_gemm<<<((N_NODES + GM - 1) / GM) * 2, 256, 0, stream>>>(x, Wp, bpk,
                                                            xb, Ubuf, Vbuf, alS, alD);
  k_hist<<<(N_EDGES + 255) / 256, 256, 0, stream>>>(ei, histP);
  k_bnd<<<(N_NODES + 255) / 256, 256, 0, stream>>>(batch, start);
  k_scan1<<<SCAN_BLOCKS, 256, 0, stream>>>(histP, rp, bsum);
  k_scan2<<<1, 256, 0, stream>>>(bsum);
  k_scan3<<<SCAN_BLOCKS, 256, 0, stream>>>(bsum, rp, histP);
  k_scatter<<<(N_EDGES + 255) / 256, 256, 0, stream>>>(ei, histP, colidx);

  // fused GAT-aggregate + GIN-sum over one L2-resident bf16 x table
  k_gatgin<<<(N_NODES + GCH - 1) / GCH, 256, 0, stream>>>(xb, alS, alD, rp, colidx,
                                                          agg4, agg);
  k_ec<<<(N_NODES + ECH - 1) / ECH, 256, 0, stream>>>(Ubuf, Vbuf, ec_w2, ec_b2, rp, colidx, batch, pooled);
  // GAT per-head transform + relu + pool
  k_gtrans<<<(N_NODES + 63) / 64, 256, 0, stream>>>(agg4, gat_w, gat_b, batch, pooled);
  // GIN MLP (h1g aliases U/V, dead after k_ec)
  k_gin1<<<(N_NODES + 63) / 64, 256, 0, stream>>>(agg, gin_w1, gin_b1, h1g);
  k_gin2<<<(N_NODES + 63) / 64, 256, 0, stream>>>(h1g, gin_w2, gin_b2, batch, pooled);

  k_pooldiv<<<(BATCH * POOLW + 255) / 256, 256, 0, stream>>>(pooled, start);

  k_heads<<<BATCH, 256, 0, stream>>>(pooled, fg1_w, fg1_b, fg2_w, fg2_b, fg3_w, fg3_b,
                                     fg4_w, fg4_b, fg5_w, fg5_b, fg6_w, fg6_b, cat);
  k_final<<<BATCH, 256, 0, stream>>>(cat, fc1_w, fc1_b, fc2_w, fc2_b, out_w, out_b, out);
}